// Round 9
// baseline (46.690 us; speedup 1.0000x reference)
//
#include <hip/hip_runtime.h>
#include <math.h>

#define BB 4
#define LL 5
#define CC 64
#define HH 128
#define WW 256
#define NTOT 16
#define HB 8               // output rows per block
#define BAND 16            // staged band rows (power of 2 for addressing)
#define HW (HH * WW)
#define NHB (HH / HB)      // 16
#define NWG (BB * CC * NHB)  // 4096

__global__ __launch_bounds__(256) void maxfusion_kernel(
    const float* __restrict__ x,        // (NTOT, C, H, W)
    const int* __restrict__ record_len, // (B,)
    const float* __restrict__ t,        // (B, L, L, 4, 4)
    float* __restrict__ out)            // (B, C, H, W)
{
    __shared__ float lds[BAND * WW];    // 16 KB: 16 rows x 256 cols

    // Balance-aware XCD swizzle: XCD <- c&7 (each XCD: 8 channels x all b
    // -> work proportional to sum(record_len), identical per XCD).
    // Within an XCD: hb fastest (adjacent bands overlap ~8 rows -> L2 hits),
    // then c_hi, then b.
    const int c_lo  = blockIdx.x & 7;
    const int inner = blockIdx.x >> 3;      // 0..511
    const int hb    = inner & (NHB - 1);    // 0..15
    const int c_hi  = (inner >> 4) & 7;     // 0..7
    const int b     = inner >> 7;           // 0..3
    const int c     = c_lo + 8 * c_hi;      // 0..63
    const int h0    = hb * HB;
    const int tid   = threadIdx.x;
    const int w     = tid;                  // one thread per output column

    const int rl = record_len[b];
    int off = 0;
    #pragma unroll
    for (int j = 0; j < BB; ++j) off += (j < b) ? record_len[j] : 0;

    const float gx = -1.0f + 2.0f * (float)w / (float)(WW - 1);

    float maxv[HB];
    #pragma unroll
    for (int hh = 0; hh < HB; ++hh) maxv[hh] = -INFINITY;

    for (int l = 0; l < rl; ++l) {
        // t[b, 0, l] — block-uniform: scalar loads + SGPR math.
        const float* tm = t + (size_t)((b * LL * LL + l) * 16);
        const float m00 = tm[0];
        const float m01 = tm[1] * ((float)HH / (float)WW);
        const float m02 = tm[3] * (2.0f / (0.8f * (float)WW));
        const float m10 = tm[4] * ((float)WW / (float)HH);
        const float m11 = tm[5];
        const float m12 = tm[7] * (2.0f / (0.8f * (float)HH));
        const float sx  = 0.5f * (float)(WW - 1);
        const float sy  = 0.5f * (float)(HH - 1);
        const float a00 = m00 * sx, a01 = m01 * sx, a02 = (m02 + 1.0f) * sx;
        const float a10 = m10 * sy, a11 = m11 * sy, a12 = (m12 + 1.0f) * sy;

        // Block-uniform band start: iy is affine in (gx,gy), so its min over
        // the block's tile [-1,1]x[gy(h0),gy(h0+HB-1)] is at a corner.
        const float gy0 = -1.0f + 2.0f * (float)h0 / (float)(HH - 1);
        const float gy1 = -1.0f + 2.0f * (float)(h0 + HB - 1) / (float)(HH - 1);
        const float iyA = -a10 + a11 * gy0 + a12;
        const float iyB =  a10 + a11 * gy0 + a12;
        const float iyC = -a10 + a11 * gy1 + a12;
        const float iyD =  a10 + a11 * gy1 + a12;
        const int ymin = (int)floorf(fminf(fminf(iyA, iyB), fminf(iyC, iyD)));

        const float* base = x + ((size_t)(off + l) * CC + c) * HW;

        // ---- stage 16-row band: aligned float4 row loads, 1 wave-load = 1 row
        __syncthreads();  // previous consume done before overwrite
        #pragma unroll
        for (int r = 0; r < 4; ++r) {
            const int flat  = r * 256 + tid;       // 0..1023
            const int j     = flat >> 6;           // band row 0..15
            const int chunk = flat & 63;           // 16B chunk in row
            const int rr    = min(max(ymin + j, 0), HH - 1);
            const float4 v  = *reinterpret_cast<const float4*>(
                                  base + (size_t)rr * WW + chunk * 4);
            *reinterpret_cast<float4*>(&lds[j * WW + chunk * 4]) = v;
        }
        __syncthreads();

        // ---- consume: 8 output rows from LDS (rare out-of-band -> global)
        #pragma unroll
        for (int hh = 0; hh < HB; ++hh) {
            const float gy = -1.0f + 2.0f * (float)(h0 + hh) / (float)(HH - 1);
            const float ix = a00 * gx + a01 * gy + a02;
            const float iy = a10 * gx + a11 * gy + a12;

            const float x0f = floorf(ix), y0f = floorf(iy);
            const float wx1 = ix - x0f, wx0 = 1.0f - wx1;
            const float wy1 = iy - y0f, wy0 = 1.0f - wy1;
            const int x0 = (int)x0f, y0 = (int)y0f;

            const bool inx = (x0 >= 0) && (x0 <= WW - 2);
            const float wxa  = inx ? wx0 : ((x0 == -1)     ? wx1 : 0.0f);
            const float wxb  = inx ? wx1 : ((x0 == WW - 1) ? wx0 : 0.0f);
            const float wy0v = ((y0 >= 0)     && (y0 <= HH - 1))     ? wy0 : 0.0f;
            const float wy1v = ((y0 + 1 >= 0) && (y0 + 1 <= HH - 1)) ? wy1 : 0.0f;

            const int k = min(max(x0, 0), WW - 2);

            const int slot   = y0 - ymin;            // >= 0 by corner-min
            const bool inband = (slot >= 0) && (slot <= BAND - 2);
            const int slotc  = min(max(slot, 0), BAND - 2);

            float2 v0 = *reinterpret_cast<const float2*>(&lds[slotc * WW + k]);
            float2 v1 = *reinterpret_cast<const float2*>(&lds[slotc * WW + WW + k]);

            if (__any(!inband)) {        // rare: large rotation tilt
                if (!inband) {
                    const int r0c = min(max(y0,     0), HH - 1);
                    const int r1c = min(max(y0 + 1, 0), HH - 1);
                    v0 = *reinterpret_cast<const float2*>(base + (size_t)r0c * WW + k);
                    v1 = *reinterpret_cast<const float2*>(base + (size_t)r1c * WW + k);
                }
            }

            const float t0 = v0.x * wxa + v0.y * wxb;
            const float t1 = v1.x * wxa + v1.y * wxb;
            maxv[hh] = fmaxf(maxv[hh], t0 * wy0v + t1 * wy1v);
        }
    }

    float* ob = out + (((size_t)b * CC + c) * HH + h0) * WW + w;
    #pragma unroll
    for (int hh = 0; hh < HB; ++hh)
        __builtin_nontemporal_store(maxv[hh], ob + (size_t)hh * WW);
}

extern "C" void kernel_launch(void* const* d_in, const int* in_sizes, int n_in,
                              void* d_out, int out_size, void* d_ws, size_t ws_size,
                              hipStream_t stream) {
    const float* x          = (const float*)d_in[0];
    const int*   record_len = (const int*)d_in[1];
    const float* t          = (const float*)d_in[2];
    float* out = (float*)d_out;

    maxfusion_kernel<<<NWG, 256, 0, stream>>>(x, record_len, t, out);
}

// Round 10
// 46.351 us; speedup vs baseline: 1.0073x; 1.0073x over previous
//
#include <hip/hip_runtime.h>
#include <math.h>

#define BB 4
#define LL 5
#define CC 64
#define HH 128
#define WW 256
#define NTOT 16
#define CG 4              // channels per block
#define HB 2              // output rows per block
#define HW (HH * WW)
#define NCG (CC / CG)     // 16
#define NHB (HH / HB)     // 64
#define NWG (BB * NCG * NHB)  // 4096

__global__ __launch_bounds__(256) void maxfusion_kernel(
    const float* __restrict__ x,        // (NTOT, C, H, W)
    const int* __restrict__ record_len, // (B,)
    const float* __restrict__ t,        // (B, L, L, 4, 4)
    float* __restrict__ out)            // (B, C, H, W)
{
    // Decode with balance-aware XCD swizzle (HW assigns XCD = blockIdx%8)
    // AND dispatch-smooth b-interleave: b sits in the LOWEST bits of the
    // per-XCD index, so every 4 consecutive blocks a CU receives carry
    // rl = {3,5,4,4} = constant 16 agent-panels -> no straggler CUs.
    // hb next (rows adjacent in time -> L2 row reuse), c_hi outermost.
    const int c_lo  = blockIdx.x & 7;       // XCD slot -> cg16 low 3 bits
    const int inner = blockIdx.x >> 3;      // 0..511
    const int b     = inner & 3;
    const int hb    = (inner >> 2) & 63;
    const int c_hi  = inner >> 8;           // 0..1
    const int cg16  = c_lo + 8 * c_hi;      // 0..15
    const int h0    = hb * HB;
    const int w     = threadIdx.x;

    const int rl = record_len[b];
    int off = 0;
    #pragma unroll
    for (int j = 0; j < BB; ++j) off += (j < b) ? record_len[j] : 0;

    const float gx = -1.0f + 2.0f * (float)w / (float)(WW - 1);

    float maxv[HB][CG];
    #pragma unroll
    for (int hh = 0; hh < HB; ++hh)
        #pragma unroll
        for (int c = 0; c < CG; ++c) maxv[hh][c] = -INFINITY;

    for (int l = 0; l < rl; ++l) {
        // t[b, 0, l] — block-uniform: scalar loads + SGPR math.
        const float* tm = t + (size_t)((b * LL * LL + l) * 16);
        const float m00 = tm[0];
        const float m01 = tm[1] * ((float)HH / (float)WW);
        const float m02 = tm[3] * (2.0f / (0.8f * (float)WW));
        const float m10 = tm[4] * ((float)WW / (float)HH);
        const float m11 = tm[5];
        const float m12 = tm[7] * (2.0f / (0.8f * (float)HH));
        const float sx  = 0.5f * (float)(WW - 1);
        const float sy  = 0.5f * (float)(HH - 1);
        const float a00 = m00 * sx, a01 = m01 * sx, a02 = (m02 + 1.0f) * sx;
        const float a10 = m10 * sy, a11 = m11 * sy, a12 = (m12 + 1.0f) * sy;

        float wxa[HB], wxb[HB], wy0v[HB], wy1v[HB];
        int off0[HB], off1[HB];
        #pragma unroll
        for (int hh = 0; hh < HB; ++hh) {
            const float gy = -1.0f + 2.0f * (float)(h0 + hh) / (float)(HH - 1);
            const float ix = a00 * gx + a01 * gy + a02;
            const float iy = a10 * gx + a11 * gy + a12;

            const float x0f = floorf(ix), y0f = floorf(iy);
            const float wx1 = ix - x0f, wx0 = 1.0f - wx1;
            const float wy1 = iy - y0f, wy0 = 1.0f - wy1;
            const int x0 = (int)x0f, y0 = (int)y0f;

            const bool inx = (x0 >= 0) && (x0 <= WW - 2);
            wxa[hh]  = inx ? wx0 : ((x0 == -1)     ? wx1 : 0.0f);
            wxb[hh]  = inx ? wx1 : ((x0 == WW - 1) ? wx0 : 0.0f);
            wy0v[hh] = ((y0 >= 0)     && (y0 <= HH - 1))     ? wy0 : 0.0f;
            wy1v[hh] = ((y0 + 1 >= 0) && (y0 + 1 <= HH - 1)) ? wy1 : 0.0f;

            const int k  = min(max(x0, 0), WW - 2);
            const int r0 = min(max(y0,     0), HH - 1);
            const int r1 = min(max(y0 + 1, 0), HH - 1);
            off0[hh] = r0 * WW + k;
            off1[hh] = r1 * WW + k;
        }

        const int n = off + l;  // always valid: off + rl <= NTOT
        const float* base = x + ((size_t)n * CC + (size_t)cg16 * CG) * HW;

        #pragma unroll
        for (int c = 0; c < CG; ++c) {
            const float* p = base + (size_t)c * HW;
            // h-pair's 4 row loads back-to-back: r1(h0) and r0(h0+1) are
            // usually the same row -> L1 hit / MSHR merge.
            const float2 qa0 = *reinterpret_cast<const float2*>(p + off0[0]);
            const float2 qa1 = *reinterpret_cast<const float2*>(p + off1[0]);
            const float2 qb0 = *reinterpret_cast<const float2*>(p + off0[1]);
            const float2 qb1 = *reinterpret_cast<const float2*>(p + off1[1]);

            const float ta0 = qa0.x * wxa[0] + qa0.y * wxb[0];
            const float ta1 = qa1.x * wxa[0] + qa1.y * wxb[0];
            maxv[0][c] = fmaxf(maxv[0][c], ta0 * wy0v[0] + ta1 * wy1v[0]);

            const float tb0 = qb0.x * wxa[1] + qb0.y * wxb[1];
            const float tb1 = qb1.x * wxa[1] + qb1.y * wxb[1];
            maxv[1][c] = fmaxf(maxv[1][c], tb0 * wy0v[1] + tb1 * wy1v[1]);
        }
    }

    float* ob = out + (((size_t)b * CC + (size_t)cg16 * CG) * HH + h0) * WW + w;
    #pragma unroll
    for (int c = 0; c < CG; ++c)
        #pragma unroll
        for (int hh = 0; hh < HB; ++hh)
            __builtin_nontemporal_store(maxv[hh][c],
                                        ob + (size_t)c * HW + (size_t)hh * WW);
}

extern "C" void kernel_launch(void* const* d_in, const int* in_sizes, int n_in,
                              void* d_out, int out_size, void* d_ws, size_t ws_size,
                              hipStream_t stream) {
    const float* x          = (const float*)d_in[0];
    const int*   record_len = (const int*)d_in[1];
    const float* t          = (const float*)d_in[2];
    float* out = (float*)d_out;

    maxfusion_kernel<<<NWG, 256, 0, stream>>>(x, record_len, t, out);
}

// Round 11
// 40.649 us; speedup vs baseline: 1.1486x; 1.1403x over previous
//
#include <hip/hip_runtime.h>
#include <math.h>

#define BB 4
#define LL 5
#define CC 64
#define HH 128
#define WW 256
#define NTOT 16
#define CG 4              // channels per block
#define HB 2              // output rows per block
#define HW (HH * WW)
#define NCG (CC / CG)     // 16
#define NHB (HH / HB)     // 64
#define NWG (BB * NCG * NHB)  // 4096

__global__ __launch_bounds__(256) void maxfusion_kernel(
    const float* __restrict__ x,        // (NTOT, C, H, W)
    const int* __restrict__ record_len, // (B,)
    const float* __restrict__ t,        // (B, L, L, 4, 4)
    float* __restrict__ out)            // (B, C, H, W)
{
    // R8 decode (best measured: 40.5us). XCD = blockIdx%8 <- cg16 low bits
    // (balance: each XCD serves all b -> sum(record_len) panels each).
    // Per-XCD order: c_hi fastest, then hb (adjacent rows close in time ->
    // L2 row reuse), b outermost (co-resident blocks share one image set;
    // R10 proved interleaving b is -13%).
    const int xcd_slot = blockIdx.x & 7;
    const int inner    = blockIdx.x >> 3;     // 0..511
    const int cg16     = xcd_slot + 8 * (inner & 1);  // 0..15
    const int rem      = inner >> 1;          // 0..255
    const int hb       = rem & 63;
    const int b        = rem >> 6;
    const int h0       = hb * HB;
    const int w        = threadIdx.x;

    const int rl = record_len[b];
    int off = 0;
    #pragma unroll
    for (int j = 0; j < BB; ++j) off += (j < b) ? record_len[j] : 0;

    const float gx = -1.0f + 2.0f * (float)w / (float)(WW - 1);

    float maxv[HB][CG];
    #pragma unroll
    for (int hh = 0; hh < HB; ++hh)
        #pragma unroll
        for (int c = 0; c < CG; ++c) maxv[hh][c] = -INFINITY;

    for (int l = 0; l < rl; ++l) {
        // t[b, 0, l] — block-uniform: scalar loads + SGPR math.
        const float* tm = t + (size_t)((b * LL * LL + l) * 16);
        const float m00 = tm[0];
        const float m01 = tm[1] * ((float)HH / (float)WW);
        const float m02 = tm[3] * (2.0f / (0.8f * (float)WW));
        const float m10 = tm[4] * ((float)WW / (float)HH);
        const float m11 = tm[5];
        const float m12 = tm[7] * (2.0f / (0.8f * (float)HH));
        const float sx  = 0.5f * (float)(WW - 1);
        const float sy  = 0.5f * (float)(HH - 1);
        const float a00 = m00 * sx, a01 = m01 * sx, a02 = (m02 + 1.0f) * sx;
        const float a10 = m10 * sy, a11 = m11 * sy, a12 = (m12 + 1.0f) * sy;

        float wxa[HB], wxb[HB], wy0v[HB], wy1v[HB];
        int off0[HB], off1[HB];
        #pragma unroll
        for (int hh = 0; hh < HB; ++hh) {
            const float gy = -1.0f + 2.0f * (float)(h0 + hh) / (float)(HH - 1);
            const float ix = a00 * gx + a01 * gy + a02;
            const float iy = a10 * gx + a11 * gy + a12;

            const float x0f = floorf(ix), y0f = floorf(iy);
            const float wx1 = ix - x0f, wx0 = 1.0f - wx1;
            const float wy1 = iy - y0f, wy0 = 1.0f - wy1;
            const int x0 = (int)x0f, y0 = (int)y0f;

            const bool inx = (x0 >= 0) && (x0 <= WW - 2);
            wxa[hh]  = inx ? wx0 : ((x0 == -1)     ? wx1 : 0.0f);
            wxb[hh]  = inx ? wx1 : ((x0 == WW - 1) ? wx0 : 0.0f);
            wy0v[hh] = ((y0 >= 0)     && (y0 <= HH - 1))     ? wy0 : 0.0f;
            wy1v[hh] = ((y0 + 1 >= 0) && (y0 + 1 <= HH - 1)) ? wy1 : 0.0f;

            const int k  = min(max(x0, 0), WW - 2);
            const int r0 = min(max(y0,     0), HH - 1);
            const int r1 = min(max(y0 + 1, 0), HH - 1);
            off0[hh] = r0 * WW + k;
            off1[hh] = r1 * WW + k;
        }

        const int n = off + l;  // always valid: off + rl <= NTOT
        const float* base = x + ((size_t)n * CC + (size_t)cg16 * CG) * HW;

        #pragma unroll
        for (int c = 0; c < CG; ++c) {
            const float* p = base + (size_t)c * HW;
            // h-pair's 4 row loads back-to-back: r1(h0) and r0(h0+1) are
            // usually the same row -> L1 hit / MSHR merge.
            const float2 qa0 = *reinterpret_cast<const float2*>(p + off0[0]);
            const float2 qa1 = *reinterpret_cast<const float2*>(p + off1[0]);
            const float2 qb0 = *reinterpret_cast<const float2*>(p + off0[1]);
            const float2 qb1 = *reinterpret_cast<const float2*>(p + off1[1]);

            const float ta0 = qa0.x * wxa[0] + qa0.y * wxb[0];
            const float ta1 = qa1.x * wxa[0] + qa1.y * wxb[0];
            maxv[0][c] = fmaxf(maxv[0][c], ta0 * wy0v[0] + ta1 * wy1v[0]);

            const float tb0 = qb0.x * wxa[1] + qb0.y * wxb[1];
            const float tb1 = qb1.x * wxa[1] + qb1.y * wxb[1];
            maxv[1][c] = fmaxf(maxv[1][c], tb0 * wy0v[1] + tb1 * wy1v[1]);
        }
    }

    float* ob = out + (((size_t)b * CC + (size_t)cg16 * CG) * HH + h0) * WW + w;
    #pragma unroll
    for (int c = 0; c < CG; ++c)
        #pragma unroll
        for (int hh = 0; hh < HB; ++hh)
            __builtin_nontemporal_store(maxv[hh][c],
                                        ob + (size_t)c * HW + (size_t)hh * WW);
}

extern "C" void kernel_launch(void* const* d_in, const int* in_sizes, int n_in,
                              void* d_out, int out_size, void* d_ws, size_t ws_size,
                              hipStream_t stream) {
    const float* x          = (const float*)d_in[0];
    const int*   record_len = (const int*)d_in[1];
    const float* t          = (const float*)d_in[2];
    float* out = (float*)d_out;

    maxfusion_kernel<<<NWG, 256, 0, stream>>>(x, record_len, t, out);
}